// Round 1
// baseline (2873.835 us; speedup 1.0000x reference)
//
#include <hip/hip_runtime.h>
#include <math.h>

#define N_TOT 32768
#define K_CB 8192
#define D_DIM 256
#define BN 64
#define BK 128
#define BD 32

#define OUT_IDX  (N_TOT * D_DIM)   // 8388608
#define OUT_LOSS (OUT_IDX + N_TOT) // 8421376
#define OUT_PERP (OUT_LOSS + 1)

// ---------------- e_sq: one wave per code, lane i reads float4 ----------------
__global__ __launch_bounds__(256) void esq_kernel(const float* __restrict__ E,
                                                  float* __restrict__ esq) {
  const int c = blockIdx.x * 4 + (threadIdx.x >> 6);
  const int lane = threadIdx.x & 63;
  const float4 v = *(const float4*)(E + (size_t)c * D_DIM + lane * 4);
  float s = v.x * v.x + v.y * v.y + v.z * v.z + v.w * v.w;
#pragma unroll
  for (int off = 32; off > 0; off >>= 1) s += __shfl_down(s, off);
  if (lane == 0) esq[c] = s;
}

// ---------------- fused distance + top-2 argmin + fp64 rescore ----------------
// Block: 256 threads as 16x16 (tx: codes, ty: rows). Per-thread 4 rows x 8 codes.
// dist = e_sq[c] - 2*dot(z,e)   (row-constant ||z||^2 dropped: argmin-invariant)
__global__ __launch_bounds__(256) void argmin_kernel(
    const float* __restrict__ Z, const float* __restrict__ E,
    const float* __restrict__ esq, float* __restrict__ out_idx_f) {
  __shared__ __align__(16) union U {
    struct { float Zt[BD][BN + 4]; float Et[BD][BK + 4]; } s;  // 25.6 KB
    struct { float b1[BN][17]; float b2[BN][17]; int i1[BN][17]; int i2[BN][17]; } r;
  } u;
  __shared__ float esq_s[BK];

  const int tid = threadIdx.x;
  const int tx = tid & 15;
  const int ty = tid >> 4;
  const int row0 = blockIdx.x * BN;

  float b1[4], b2[4];
  int i1[4], i2[4];
#pragma unroll
  for (int i = 0; i < 4; i++) { b1[i] = 3.4e38f; b2[i] = 3.4e38f; i1[i] = 0; i2[i] = 0; }

  for (int kt = 0; kt < K_CB; kt += BK) {
    __syncthreads();  // prior epilogue's esq_s reads done before restage
    if (tid < BK) esq_s[tid] = esq[kt + tid];

    float acc[4][8];
#pragma unroll
    for (int i = 0; i < 4; i++)
#pragma unroll
      for (int j = 0; j < 8; j++) acc[i][j] = 0.0f;

    for (int dt = 0; dt < D_DIM; dt += BD) {
      __syncthreads();  // previous chunk's LDS reads done before overwrite
      {
        const int r = tid >> 3;              // 0..31
        const int dd = (tid & 7) << 2;       // 0,4,..28
        const float4 a = *(const float4*)(Z + (size_t)(row0 + r) * D_DIM + dt + dd);
        u.s.Zt[dd + 0][r] = a.x; u.s.Zt[dd + 1][r] = a.y;
        u.s.Zt[dd + 2][r] = a.z; u.s.Zt[dd + 3][r] = a.w;
        const float4 b = *(const float4*)(Z + (size_t)(row0 + r + 32) * D_DIM + dt + dd);
        u.s.Zt[dd + 0][r + 32] = b.x; u.s.Zt[dd + 1][r + 32] = b.y;
        u.s.Zt[dd + 2][r + 32] = b.z; u.s.Zt[dd + 3][r + 32] = b.w;
#pragma unroll
        for (int jj = 0; jj < 4; jj++) {
          const float4 e = *(const float4*)(E + (size_t)(kt + r + 32 * jj) * D_DIM + dt + dd);
          u.s.Et[dd + 0][r + 32 * jj] = e.x; u.s.Et[dd + 1][r + 32 * jj] = e.y;
          u.s.Et[dd + 2][r + 32 * jj] = e.z; u.s.Et[dd + 3][r + 32 * jj] = e.w;
        }
      }
      __syncthreads();
#pragma unroll 4
      for (int d = 0; d < BD; d++) {
        float zr[4], er[8];
        const float4 z4 = *(const float4*)&u.s.Zt[d][ty * 4];
        zr[0] = z4.x; zr[1] = z4.y; zr[2] = z4.z; zr[3] = z4.w;
        const float4 e0 = *(const float4*)&u.s.Et[d][tx * 8];
        const float4 e1 = *(const float4*)&u.s.Et[d][tx * 8 + 4];
        er[0] = e0.x; er[1] = e0.y; er[2] = e0.z; er[3] = e0.w;
        er[4] = e1.x; er[5] = e1.y; er[6] = e1.z; er[7] = e1.w;
#pragma unroll
        for (int i = 0; i < 4; i++)
#pragma unroll
          for (int j = 0; j < 8; j++) acc[i][j] += zr[i] * er[j];
      }
    }
    // epilogue: merge this K-tile into per-thread top-2 (candidates ascend in c)
#pragma unroll
    for (int j = 0; j < 8; j++) {
      const int c = kt + tx * 8 + j;
      const float es = esq_s[tx * 8 + j];
#pragma unroll
      for (int i = 0; i < 4; i++) {
        const float dist = es - 2.0f * acc[i][j];
        if (dist < b1[i]) { b2[i] = b1[i]; i2[i] = i1[i]; b1[i] = dist; i1[i] = c; }
        else if (dist < b2[i]) { b2[i] = dist; i2[i] = c; }
      }
    }
  }

  __syncthreads();  // all LDS compute reads done; reuse union for reduction
#pragma unroll
  for (int i = 0; i < 4; i++) {
    u.r.b1[ty * 4 + i][tx] = b1[i];
    u.r.b2[ty * 4 + i][tx] = b2[i];
    u.r.i1[ty * 4 + i][tx] = i1[i];
    u.r.i2[ty * 4 + i][tx] = i2[i];
  }
  __syncthreads();
  if (tid < BN) {
    float B1 = 3.4e38f, B2 = 3.4e38f;
    int I1 = 0, I2 = 0;
    for (int t = 0; t < 16; t++) {
      const float d1v = u.r.b1[tid][t]; const int c1v = u.r.i1[tid][t];
      const float d2v = u.r.b2[tid][t]; const int c2v = u.r.i2[tid][t];
      if (d1v < B1 || (d1v == B1 && c1v < I1)) { B2 = B1; I2 = I1; B1 = d1v; I1 = c1v; }
      else if (d1v < B2 || (d1v == B2 && c1v < I2)) { B2 = d1v; I2 = c2v == c1v ? I2 : c1v; }
      if (d2v < B1 || (d2v == B1 && c2v < I1)) { B2 = B1; I2 = I1; B1 = d2v; I1 = c2v; }
      else if (d2v < B2 || (d2v == B2 && c2v < I2)) { B2 = d2v; I2 = c2v; }
    }
    // fp64 rescore of top-2: resolves fp32 near-ties against the true distance
    const int row = row0 + tid;
    const float* zp = Z + (size_t)row * D_DIM;
    const float* ep1 = E + (size_t)I1 * D_DIM;
    const float* ep2 = E + (size_t)I2 * D_DIM;
    double dd1 = 0.0, dd2 = 0.0;
    for (int d = 0; d < D_DIM; d += 4) {
      const float4 zv = *(const float4*)(zp + d);
      const float4 e1v = *(const float4*)(ep1 + d);
      const float4 e2v = *(const float4*)(ep2 + d);
      double t;
      t = (double)zv.x - (double)e1v.x; dd1 += t * t;
      t = (double)zv.y - (double)e1v.y; dd1 += t * t;
      t = (double)zv.z - (double)e1v.z; dd1 += t * t;
      t = (double)zv.w - (double)e1v.w; dd1 += t * t;
      t = (double)zv.x - (double)e2v.x; dd2 += t * t;
      t = (double)zv.y - (double)e2v.y; dd2 += t * t;
      t = (double)zv.z - (double)e2v.z; dd2 += t * t;
      t = (double)zv.w - (double)e2v.w; dd2 += t * t;
    }
    int fin = I1;
    if (dd2 < dd1 || (dd2 == dd1 && I2 < I1)) fin = I2;
    out_idx_f[row] = (float)fin;
  }
}

// ---------------- gather z_q, accumulate loss sum + counts ----------------
__global__ __launch_bounds__(256) void gather_kernel(
    const float* __restrict__ Z, const float* __restrict__ E,
    const float* __restrict__ idx_f, float* __restrict__ zq_out,
    float* __restrict__ counts, float* __restrict__ loss_sum) {
  const int row = blockIdx.x;
  const int t = threadIdx.x;
  const int c = (int)idx_f[row];
  const float e = E[(size_t)c * D_DIM + t];
  const float z = Z[(size_t)row * D_DIM + t];
  zq_out[(size_t)row * D_DIM + t] = e;
  float sq = (z - e) * (z - e);
#pragma unroll
  for (int off = 32; off > 0; off >>= 1) sq += __shfl_down(sq, off);
  __shared__ float wsum[4];
  if ((t & 63) == 0) wsum[t >> 6] = sq;
  __syncthreads();
  if (t == 0) {
    atomicAdd(loss_sum, wsum[0] + wsum[1] + wsum[2] + wsum[3]);
    atomicAdd(&counts[c], 1.0f);
  }
}

// ---------------- loss scale + perplexity ----------------
__global__ __launch_bounds__(256) void final_kernel(
    const float* __restrict__ counts, const float* __restrict__ loss_sum,
    float* __restrict__ out) {
  const int t = threadIdx.x;
  float h = 0.0f;
  for (int k = t; k < K_CB; k += 256) {
    const float p = counts[k] * (1.0f / (float)N_TOT);
    h += p * logf(p + 1e-12f);
  }
#pragma unroll
  for (int off = 32; off > 0; off >>= 1) h += __shfl_down(h, off);
  __shared__ float ws4[4];
  if ((t & 63) == 0) ws4[t >> 6] = h;
  __syncthreads();
  if (t == 0) {
    const float H = ws4[0] + ws4[1] + ws4[2] + ws4[3];
    out[OUT_LOSS] = 1.25f * loss_sum[0] * (1.0f / (float)(N_TOT * D_DIM));
    out[OUT_PERP] = expf(-H);
  }
}

extern "C" void kernel_launch(void* const* d_in, const int* in_sizes, int n_in,
                              void* d_out, int out_size, void* d_ws, size_t ws_size,
                              hipStream_t stream) {
  (void)in_sizes; (void)n_in; (void)out_size; (void)ws_size;
  const float* Z = (const float*)d_in[0];
  const float* E = (const float*)d_in[1];
  float* out = (float*)d_out;
  char* ws = (char*)d_ws;
  float* counts   = (float*)ws;              // 8192 floats
  float* loss_sum = (float*)(ws + 32768);    // 1 float
  float* esq      = (float*)(ws + 33024);    // 8192 floats

  hipMemsetAsync(ws, 0, 32772, stream);  // zero counts + loss_sum (ws is poisoned)
  esq_kernel<<<dim3(K_CB / 4), dim3(256), 0, stream>>>(E, esq);
  argmin_kernel<<<dim3(N_TOT / BN), dim3(256), 0, stream>>>(Z, E, esq, out + OUT_IDX);
  gather_kernel<<<dim3(N_TOT), dim3(256), 0, stream>>>(Z, E, out + OUT_IDX, out, counts, loss_sum);
  final_kernel<<<dim3(1), dim3(256), 0, stream>>>(counts, loss_sum, out);
}